// Round 3
// baseline (39919.254 us; speedup 1.0000x reference)
//
#include <hip/hip_runtime.h>
#include <hip/hip_cooperative_groups.h>
#include <math.h>

namespace cg = cooperative_groups;

// =====================================================================
// AttendAndSpell persistent-kernel v2.
// Fix vs v1: static LDS cut 44.5KB -> 18.7KB so 2 blocks/CU fit the
// cooperative-launch occupancy check; grid clamped by occupancy query and
// every phase is a virtual-block loop (correct at any grid size).
// =====================================================================

#define B_   128
#define HID_ 512
#define VOC_ 64
#define T_   128
#define NCU_ 256

// workspace offsets (floats)
#define S0T_OFF    0u
#define CS0T_OFF   65536u
#define S1T_OFF    131072u
#define CS1T_OFF   196608u
#define SQTB_OFF   262144u     // [b][512]
#define AA_OFF     327680u     // [q][512][128]
#define AM_OFF     589824u     // [q][128]
#define AL_OFF     590336u
#define PART_OFF   590848u     // [16][2048][128]
#define AMAT_OFF   4785152u    // 512x512
#define W1PSI_OFF  5047296u    // 2048x512
#define BIAS0_OFF  6095872u
#define BIAS1_OFF  6097920u
#define VVEC_OFF   6099968u
#define WOHT_OFF   6100480u    // [2048][64]
#define ZB_OFF     6231552u    // 128 ints

#define TF_TINY 1.17549435e-38f

// ----------------------- threefry2x32 ---------------------------------
__device__ __forceinline__ void tf2x32(unsigned k0, unsigned k1,
                                       unsigned& x0, unsigned& x1) {
  unsigned ks2 = k0 ^ k1 ^ 0x1BD11BDAu;
  const unsigned ks[3] = {k0, k1, ks2};
  const int rot0[4] = {13, 15, 26, 6};
  const int rot1[4] = {17, 29, 16, 24};
  x0 += ks[0]; x1 += ks[1];
  #pragma unroll
  for (int i = 0; i < 5; ++i) {
    #pragma unroll
    for (int r = 0; r < 4; ++r) {
      int rr = (i & 1) ? rot1[r] : rot0[r];
      x0 += x1;
      x1 = (x1 << rr) | (x1 >> (32 - rr));
      x1 ^= x0;
    }
    x0 += ks[(i + 1) % 3];
    x1 += ks[(i + 2) % 3] + (unsigned)(i + 1);
  }
}

__device__ __forceinline__ float bits_to_unit(unsigned bits) {
  return __uint_as_float((bits >> 9) | 0x3f800000u) - 1.0f;
}

__device__ __forceinline__ float sigm(float x) { return 1.0f / (1.0f + expf(-x)); }

// ----------------------- one-time precompute ---------------------------
__global__ __launch_bounds__(256) void k_fold(
    const float* __restrict__ psi_w, const float* __restrict__ phi_b,
    const float* __restrict__ w_ih0, const float* __restrict__ psi_b,
    const float* __restrict__ b_ih0, const float* __restrict__ b_hh0,
    const float* __restrict__ b_ih1, const float* __restrict__ b_hh1,
    float* __restrict__ vvec, float* __restrict__ bias0,
    float* __restrict__ bias1, float* __restrict__ wohT) {
  int gid = blockIdx.x * 256 + threadIdx.x;
  if (gid < 512) {
    float acc = 0.f;
    for (int j = 0; j < 512; ++j) acc += psi_w[j * 512 + gid] * phi_b[j];
    vvec[gid] = acc;
  } else if (gid < 2560) {
    int j = gid - 512;
    float acc = b_ih0[j] + b_hh0[j];
    const float* wr = w_ih0 + (size_t)j * 576 + 64;
    for (int d = 0; d < 512; ++d) acc += wr[d] * psi_b[d];
    bias0[j] = acc;
  } else if (gid < 4608) {
    int j = gid - 2560;
    bias1[j] = b_ih1[j] + b_hh1[j];
  } else if (gid < 4608 + 131072) {
    int idx = gid - 4608;
    int j = idx >> 6, v = idx & 63;
    wohT[idx] = w_ih0[(size_t)j * 576 + v];
  }
}

// C[m][n] = sum_j A[j][m]*B[j][n]
__global__ __launch_bounds__(256) void k_gemm_tn(
    const float* __restrict__ A, const float* __restrict__ B, float* __restrict__ C,
    int K, int lda, int ldb, int ldc) {
  __shared__ float As[32][33], Bs[32][33];
  int n0 = blockIdx.x * 32, m0 = blockIdx.y * 32;
  int t = threadIdx.x, tx = t & 31, ty = t >> 5;
  float acc[4] = {0.f, 0.f, 0.f, 0.f};
  for (int k0 = 0; k0 < K; k0 += 32) {
    for (int l = t; l < 1024; l += 256) {
      int jj = l >> 5, mm = l & 31;
      As[jj][mm] = A[(size_t)(k0 + jj) * lda + m0 + mm];
      Bs[jj][mm] = B[(size_t)(k0 + jj) * ldb + n0 + mm];
    }
    __syncthreads();
    #pragma unroll 8
    for (int jj = 0; jj < 32; ++jj) {
      float bv = Bs[jj][tx];
      #pragma unroll
      for (int q = 0; q < 4; ++q) acc[q] += As[jj][ty + 8 * q] * bv;
    }
    __syncthreads();
  }
  #pragma unroll
  for (int q = 0; q < 4; ++q) C[(size_t)(m0 + ty + 8 * q) * ldc + n0 + tx] = acc[q];
}

// C[m][n] = sum_k A[m][aoff+k]*B[k][n]
__global__ __launch_bounds__(256) void k_gemm_nn(
    const float* __restrict__ A, const float* __restrict__ B, float* __restrict__ C,
    int K, int lda, int aoff, int ldb, int ldc) {
  __shared__ float As[32][33], Bs[32][33];
  int n0 = blockIdx.x * 32, m0 = blockIdx.y * 32;
  int t = threadIdx.x, tx = t & 31, ty = t >> 5;
  float acc[4] = {0.f, 0.f, 0.f, 0.f};
  for (int k0 = 0; k0 < K; k0 += 32) {
    for (int l = t; l < 1024; l += 256) {
      int r = l >> 5, c = l & 31;
      As[c][r] = A[(size_t)(m0 + r) * lda + aoff + k0 + c];
      Bs[r][c] = B[(size_t)(k0 + r) * ldb + n0 + c];
    }
    __syncthreads();
    #pragma unroll 8
    for (int kk = 0; kk < 32; ++kk) {
      float bv = Bs[kk][tx];
      #pragma unroll
      for (int q = 0; q < 4; ++q) acc[q] += As[kk][ty + 8 * q] * bv;
    }
    __syncthreads();
  }
  #pragma unroll
  for (int q = 0; q < 4; ++q) C[(size_t)(m0 + ty + 8 * q) * ldc + n0 + tx] = acc[q];
}

__global__ __launch_bounds__(256) void k_init(const float* __restrict__ vvec,
                                              const int* __restrict__ y,
                                              float* __restrict__ sqtb,
                                              int* __restrict__ z) {
  int lin = blockIdx.x * 256 + threadIdx.x;
  if (lin < 65536) sqtb[lin] = vvec[lin & 511];
  if (lin < 128) z[lin] = y[lin * (T_ + 1)];
}

// ----------------------- persistent phase helpers ----------------------
// GEMM virtual block: vb -> s (K-slice, 0..15), jt (j-tile of 128, 0..15),
// bh (batch half, 0..1). Tile: 64b x 128j x 64k, per-thread 4b x 8j.
// s<8 -> first K-half (X0/W0), s>=8 -> second (X1/W1). X0==nullptr means
// X is the attention-combine of aa partials.
__device__ __forceinline__ void gemm_slice(
    int jt, int s, int bh, int t,
    const float* XT0, const float* XT1,
    const float* aa, const float* am, const float* al,
    const float* W0, const float* W1,
    float* part, float* smem) {
  float* Xs  = smem;          // 16 x 64 = 1024
  float* Wsm = smem + 1024;   // 16 x 132 = 2112
  float* wql = smem + 3136;   // 128 x 4 = 512
  const float* W  = (s < 8) ? W0 : W1;
  const float* XT = (s < 8) ? XT0 : XT1;
  int kslice = (s & 7) * 64;

  if (XT == nullptr && t < 128) {
    int b = t;
    float m0 = am[b], m1 = am[128 + b], m2 = am[256 + b], m3 = am[384 + b];
    float M = fmaxf(fmaxf(m0, m1), fmaxf(m2, m3));
    float e0 = expf(m0 - M), e1 = expf(m1 - M), e2 = expf(m2 - M), e3 = expf(m3 - M);
    float L = e0 * al[b] + e1 * al[128 + b] + e2 * al[256 + b] + e3 * al[384 + b];
    float inv = 1.0f / L;
    wql[b * 4 + 0] = e0 * inv; wql[b * 4 + 1] = e1 * inv;
    wql[b * 4 + 2] = e2 * inv; wql[b * 4 + 3] = e3 * inv;
  }

  float acc[4][8];
  #pragma unroll
  for (int i = 0; i < 4; ++i)
    #pragma unroll
    for (int j = 0; j < 8; ++j) acc[i][j] = 0.f;
  int b0 = (t & 15) * 4, j0 = (t >> 4) * 8;

  for (int kc = 0; kc < 64; kc += 16) {
    int kb = kslice + kc;
    __syncthreads();
    if (XT == nullptr) {
      for (int l = t; l < 1024; l += 256) {
        int kk = l >> 6, bl = l & 63, b = bh * 64 + bl;
        const float* ar = aa + (size_t)(kb + kk) * 128 + b;
        Xs[kk * 64 + bl] = wql[b * 4 + 0] * ar[0]      + wql[b * 4 + 1] * ar[65536]
                         + wql[b * 4 + 2] * ar[131072] + wql[b * 4 + 3] * ar[196608];
      }
    } else {
      for (int l = t; l < 256; l += 256) {
        int kk = l >> 4, b4 = (l & 15) * 4;
        *(float4*)(Xs + kk * 64 + b4) =
            *(const float4*)(XT + (size_t)(kb + kk) * 128 + bh * 64 + b4);
      }
    }
    for (int l = t; l < 512; l += 256) {
      int j = l & 127, k4 = (l >> 7) * 4;
      float4 wv = *(const float4*)(W + (size_t)(jt * 128 + j) * 512 + kb + k4);
      Wsm[(k4 + 0) * 132 + j] = wv.x;
      Wsm[(k4 + 1) * 132 + j] = wv.y;
      Wsm[(k4 + 2) * 132 + j] = wv.z;
      Wsm[(k4 + 3) * 132 + j] = wv.w;
    }
    __syncthreads();
    #pragma unroll
    for (int k = 0; k < 16; ++k) {
      float4 x0 = *(const float4*)(Xs + k * 64 + b0);
      float4 w0 = *(const float4*)(Wsm + k * 132 + j0);
      float4 w1 = *(const float4*)(Wsm + k * 132 + j0 + 4);
      float xr[4] = {x0.x, x0.y, x0.z, x0.w};
      float wr[8] = {w0.x, w0.y, w0.z, w0.w, w1.x, w1.y, w1.z, w1.w};
      #pragma unroll
      for (int bb = 0; bb < 4; ++bb)
        #pragma unroll
        for (int jj = 0; jj < 8; ++jj)
          acc[bb][jj] = fmaf(xr[bb], wr[jj], acc[bb][jj]);
    }
  }
  __syncthreads();  // all staging readers done before caller may reuse smem
  #pragma unroll
  for (int jj = 0; jj < 8; ++jj) {
    float* pr = part + (size_t)(s * 2048 + jt * 128 + j0 + jj) * 128 + bh * 64 + b0;
    *(float4*)pr = make_float4(acc[0][jj], acc[1][jj], acc[2][jj], acc[3][jj]);
  }
}

__device__ __forceinline__ void cell_phase(
    int vb, int t, const float* part, const float* bias,
    const float* wohT, const int* z, float* sT, float* cT) {
  int lin = vb * 256 + t;            // vb < 256 -> 65536 elems
  int d = lin >> 7, b = lin & 127;
  int zb = wohT ? z[b] : 0;
  float g4[4];
  #pragma unroll
  for (int g = 0; g < 4; ++g) {
    int j = g * 512 + d;
    float sum = bias[j];
    if (wohT) sum += wohT[j * 64 + zb];
    const float* pr = part + (size_t)j * 128 + b;
    #pragma unroll
    for (int s16 = 0; s16 < 16; ++s16) sum += pr[(size_t)s16 * 262144];
    g4[g] = sum;
  }
  float ig = sigm(g4[0]), fg = sigm(g4[1]);
  float gg = tanhf(g4[2]), og = sigm(g4[3]);
  int idx = d * 128 + b;
  float cn = fg * cT[idx] + ig * gg;
  cT[idx] = cn;
  sT[idx] = og * tanhf(cn);
}

// ----------------------- the persistent kernel -------------------------
__global__ __launch_bounds__(256, 2) void k_persist(
    const float* __restrict__ h, const float* __restrict__ w_hh0,
    const float* __restrict__ w_ih1, const float* __restrict__ w_hh1,
    const float* __restrict__ outw, const float* __restrict__ outb,
    const int* __restrict__ y, float* __restrict__ out, float* __restrict__ ws) {
  cg::grid_group grid = cg::this_grid();
  __shared__ float smem[4672];   // 18.7 KB -> 2+ blocks/CU

  float* s0T   = ws + S0T_OFF;
  float* cs0T  = ws + CS0T_OFF;
  float* s1T   = ws + S1T_OFF;
  float* cs1T  = ws + CS1T_OFF;
  float* sqtb  = ws + SQTB_OFF;
  float* aa    = ws + AA_OFF;
  float* am    = ws + AM_OFF;
  float* al    = ws + AL_OFF;
  float* part  = ws + PART_OFF;
  float* Amat  = ws + AMAT_OFF;
  float* W1psi = ws + W1PSI_OFF;
  float* bias0 = ws + BIAS0_OFF;
  float* bias1 = ws + BIAS1_OFF;
  float* vvec  = ws + VVEC_OFF;
  float* wohT  = ws + WOHT_OFF;
  int*   z     = (int*)(ws + ZB_OFF);

  int nb = gridDim.x, t = threadIdx.x;

  for (int st = 0; st < T_; ++st) {
    // ------- S1: attention partials, 4 q-blocks per batch --------------
    for (int vb = blockIdx.x; vb < 512; vb += nb) {
      int b = vb >> 2, q = vb & 3;
      float* sq = smem;          // 512
      float* hs = smem + 512;    // 8*512
      float* es = smem + 4608;   // 8
      float* ps = smem + 4616;   // 8
      sq[t]       = sqtb[b * 512 + t];
      sq[t + 256] = sqtb[b * 512 + 256 + t];
      const float* hb = h + (size_t)b * 512 * 512;
      int krow = t >> 5, g = t & 31;
      float m = -INFINITY, l = 0.f, a0 = 0.f, a1 = 0.f;
      for (int r0 = q * 128; r0 < q * 128 + 128; r0 += 8) {
        __syncthreads();
        const float* hr = hb + (size_t)(r0 + krow) * 512;
        float ep = 0.f;
        #pragma unroll
        for (int i = 0; i < 4; ++i) {
          int d = i * 128 + g * 4;
          float4 hv = *(const float4*)(hr + d);
          float4 sv = *(const float4*)(sq + d);
          ep += hv.x * sv.x + hv.y * sv.y + hv.z * sv.z + hv.w * sv.w;
          *(float4*)(&hs[krow * 512 + d]) = hv;
        }
        ep += __shfl_xor(ep, 1);
        ep += __shfl_xor(ep, 2);
        ep += __shfl_xor(ep, 4);
        ep += __shfl_xor(ep, 8);
        ep += __shfl_xor(ep, 16);
        if (g == 0) es[krow] = ep;
        __syncthreads();
        float mc = fmaxf(fmaxf(fmaxf(es[0], es[1]), fmaxf(es[2], es[3])),
                         fmaxf(fmaxf(es[4], es[5]), fmaxf(es[6], es[7])));
        float mn = fmaxf(m, mc);
        if (t < 8) ps[t] = expf(es[t] - mn);
        __syncthreads();
        float sc = expf(m - mn), ls = 0.f;
        float n0 = a0 * sc, n1 = a1 * sc;
        #pragma unroll
        for (int k = 0; k < 8; ++k) {
          float p = ps[k];
          ls += p;
          n0 += p * hs[k * 512 + t];
          n1 += p * hs[k * 512 + t + 256];
        }
        m = mn; l = l * sc + ls; a0 = n0; a1 = n1;
      }
      aa[(size_t)(q * 512 + t) * 128 + b] = a0;
      aa[(size_t)(q * 512 + t + 256) * 128 + b] = a1;
      if (t == 0) { am[q * 128 + b] = m; al[q * 128 + b] = l; }
      __syncthreads();
    }
    grid.sync();

    // ------- S2: LSTM0 gate GEMM (attn combine fused) ------------------
    for (int vb = blockIdx.x; vb < 512; vb += nb)
      gemm_slice((vb >> 1) & 15, vb >> 5, vb & 1, t, nullptr, s0T,
                 aa, am, al, W1psi, w_hh0, part, smem);
    grid.sync();

    // ------- S3: cell0 -------------------------------------------------
    for (int vb = blockIdx.x; vb < 256; vb += nb)
      cell_phase(vb, t, part, bias0, wohT, z, s0T, cs0T);
    grid.sync();

    // ------- S4: LSTM1 gate GEMM ---------------------------------------
    for (int vb = blockIdx.x; vb < 512; vb += nb)
      gemm_slice((vb >> 1) & 15, vb >> 5, vb & 1, t, s0T, s1T,
                 aa, am, al, w_ih1, w_hh1, part, smem);
    grid.sync();

    // ------- S5: cell1 -------------------------------------------------
    for (int vb = blockIdx.x; vb < 256; vb += nb)
      cell_phase(vb, t, part, bias1, nullptr, z, s1T, cs1T);
    grid.sync();

    // ------- S6: logits+sample (vb<128) | next-step sqt (128..255) -----
    for (int vb = blockIdx.x; vb < 256; vb += nb) {
      __syncthreads();
      if (vb < 128) {
        int b = vb;
        float* sl  = smem;
        float* red = smem + 512;
        for (int i = t; i < 512; i += 256) sl[i] = s1T[(size_t)i * 128 + b];
        __syncthreads();
        int v = t & 63, kg = t >> 6;
        const float* wr = outw + (size_t)v * 512 + kg * 128;
        const float* sr = sl + kg * 128;
        float sum = 0.f;
        #pragma unroll 8
        for (int k = 0; k < 128; k += 4) {
          float4 w4 = *(const float4*)(wr + k);
          float4 s4 = *(const float4*)(sr + k);
          sum += w4.x * s4.x + w4.y * s4.y + w4.z * s4.z + w4.w * s4.w;
        }
        red[kg * 64 + v] = sum;
        __syncthreads();
        if (t < 64) {
          float o = red[t] + red[64 + t] + red[128 + t] + red[192 + t] + outb[t];
          out[((size_t)b * T_ + st) * VOC_ + t] = o;
          unsigned ka = 0u, kb2 = (unsigned)st;
          tf2x32(0u, 42u, ka, kb2);
          unsigned k1a = 0u, k1b = 0u;
          tf2x32(ka, kb2, k1a, k1b);
          unsigned x0 = 0u, x1 = (unsigned)(b * 64 + t);
          tf2x32(k1a, k1b, x0, x1);
          float f = bits_to_unit(x0 ^ x1);
          float u = fmaxf(TF_TINY, f * (1.0f - TF_TINY) + TF_TINY);
          float val = o - logf(-logf(u));
          int idx = t;
          #pragma unroll
          for (int off = 1; off < 64; off <<= 1) {
            float ov = __shfl_xor(val, off);
            int oi = __shfl_xor(idx, off);
            if (ov > val || (ov == val && oi < idx)) { val = ov; idx = oi; }
          }
          if (t == 0) {
            unsigned k2a = 0u, k2b = 1u;
            tf2x32(ka, kb2, k2a, k2b);
            unsigned y0 = 0u, y1 = (unsigned)b;
            tf2x32(k2a, k2b, y0, y1);
            float ub = bits_to_unit(y0 ^ y1);
            z[b] = (ub < 0.1f) ? idx : y[b * (T_ + 1) + st + 1];
          }
        }
        __syncthreads();
      } else {
        int dq = (vb - 128) * 4;
        float* As = smem;          // 32*128
        int b = t & 127, dh = (t >> 7) * 2;
        float acc0 = vvec[dq + dh], acc1 = vvec[dq + dh + 1];
        const float* Ar0 = Amat + (size_t)(dq + dh) * 512;
        const float* Ar1 = Amat + (size_t)(dq + dh + 1) * 512;
        for (int k0 = 0; k0 < 512; k0 += 32) {
          for (int l = t; l < 1024; l += 256) {
            int kk = l >> 5, b4 = (l & 31) * 4;
            *(float4*)(As + kk * 128 + b4) =
                *(const float4*)(s1T + (size_t)(k0 + kk) * 128 + b4);
          }
          __syncthreads();
          #pragma unroll 8
          for (int kk = 0; kk < 32; ++kk) {
            float x = As[kk * 128 + b];
            acc0 = fmaf(x, Ar0[k0 + kk], acc0);
            acc1 = fmaf(x, Ar1[k0 + kk], acc1);
          }
          __syncthreads();
        }
        *(float2*)(sqtb + (size_t)b * 512 + dq + dh) = make_float2(acc0, acc1);
      }
    }
    grid.sync();
  }
}

// =====================================================================
extern "C" void kernel_launch(void* const* d_in, const int* in_sizes, int n_in,
                              void* d_out, int out_size, void* d_ws, size_t ws_size,
                              hipStream_t stream) {
  const float* h     = (const float*)d_in[0];
  const float* phi_w = (const float*)d_in[1];
  const float* phi_b = (const float*)d_in[2];
  const float* psi_w = (const float*)d_in[3];
  const float* psi_b = (const float*)d_in[4];
  const float* w_ih0 = (const float*)d_in[5];
  const float* w_hh0 = (const float*)d_in[6];
  const float* b_ih0 = (const float*)d_in[7];
  const float* b_hh0 = (const float*)d_in[8];
  const float* w_ih1 = (const float*)d_in[9];
  const float* w_hh1 = (const float*)d_in[10];
  const float* b_ih1 = (const float*)d_in[11];
  const float* b_hh1 = (const float*)d_in[12];
  const float* out_w = (const float*)d_in[13];
  const float* out_b = (const float*)d_in[14];
  const int*   y     = (const int*)d_in[15];

  float* out = (float*)d_out;
  float* ws  = (float*)d_ws;

  float* Amat  = ws + AMAT_OFF;
  float* W1psi = ws + W1PSI_OFF;
  float* bias0 = ws + BIAS0_OFF;
  float* bias1 = ws + BIAS1_OFF;
  float* vvec  = ws + VVEC_OFF;
  float* wohT  = ws + WOHT_OFF;
  float* sqtb  = ws + SQTB_OFF;
  int*   z     = (int*)(ws + ZB_OFF);

  // zero recurrent states (s0T, cs0T, s1T, cs1T contiguous)
  hipMemsetAsync(ws, 0, 4u * 65536u * sizeof(float), stream);

  k_fold<<<531, 256, 0, stream>>>(psi_w, phi_b, w_ih0, psi_b, b_ih0, b_hh0,
                                  b_ih1, b_hh1, vvec, bias0, bias1, wohT);
  k_gemm_tn<<<dim3(16, 16), 256, 0, stream>>>(psi_w, phi_w, Amat, 512, 512, 512, 512);
  k_gemm_nn<<<dim3(16, 64), 256, 0, stream>>>(w_ih0, psi_w, W1psi, 512, 576, 64, 512, 512);
  k_init<<<256, 256, 0, stream>>>(vvec, y, sqtb, z);

  // grid clamped by occupancy so the cooperative launch always validates;
  // phases are virtual-block loops -> correct at any grid size.
  int maxB = 0;
  hipError_t oe = hipOccupancyMaxActiveBlocksPerMultiprocessor(
      &maxB, (const void*)k_persist, 256, 0);
  int grid = 256;
  if (oe == hipSuccess && maxB >= 1) {
    grid = maxB * NCU_;
    if (grid > 512) grid = 512;
  }

  void* args[] = {(void*)&h, (void*)&w_hh0, (void*)&w_ih1, (void*)&w_hh1,
                  (void*)&out_w, (void*)&out_b, (void*)&y, (void*)&out, (void*)&ws};
  hipLaunchCooperativeKernel((const void*)k_persist, dim3(grid), dim3(256),
                             args, 0, stream);
}

// Round 4
// 17585.843 us; speedup vs baseline: 2.2700x; 2.2700x over previous
//
#include <hip/hip_runtime.h>
#include <math.h>

// =====================================================================
// AttendAndSpell v3: graph of 3 fused kernels per step (no cooperative
// sync — round-3 showed grid.sync() ~45us each on MI355X).
//  K_step: per-batch fused  s1col -> sqt -> logits -> sample -> attention
//  K_lstm: full-K gate GEMM with LSTM cell fused in epilogue (no split-K
//          partial buffer), X read from L2 in [k][b] layout, W scalar.
// All fp32 (sampling decisions need fp32; no fp32 MFMA on CDNA4).
// =====================================================================

#define B_   128
#define HID_ 512
#define VOC_ 64
#define T_   128

// workspace offsets (floats): states ping-pong
#define S0A_OFF    0u
#define S0B_OFF    65536u
#define CS0_OFF    131072u
#define S1A_OFF    196608u
#define S1B_OFF    262144u
#define CS1_OFF    327680u
#define CTX_OFF    393216u     // ctxT [512][128]
#define AMAT_OFF   458752u     // 512x512
#define W1PSI_OFF  720896u     // 2048x512
#define BIAS0_OFF  1769472u
#define BIAS1_OFF  1771520u
#define VVEC_OFF   1773568u
#define WOHT_OFF   1774080u    // [2048][64]
#define ZB_OFF     1905152u    // 128 ints

#define TF_TINY 1.17549435e-38f

// ----------------------- threefry2x32 ---------------------------------
__device__ __forceinline__ void tf2x32(unsigned k0, unsigned k1,
                                       unsigned& x0, unsigned& x1) {
  unsigned ks2 = k0 ^ k1 ^ 0x1BD11BDAu;
  const unsigned ks[3] = {k0, k1, ks2};
  const int rot0[4] = {13, 15, 26, 6};
  const int rot1[4] = {17, 29, 16, 24};
  x0 += ks[0]; x1 += ks[1];
  #pragma unroll
  for (int i = 0; i < 5; ++i) {
    #pragma unroll
    for (int r = 0; r < 4; ++r) {
      int rr = (i & 1) ? rot1[r] : rot0[r];
      x0 += x1;
      x1 = (x1 << rr) | (x1 >> (32 - rr));
      x1 ^= x0;
    }
    x0 += ks[(i + 1) % 3];
    x1 += ks[(i + 2) % 3] + (unsigned)(i + 1);
  }
}

__device__ __forceinline__ float bits_to_unit(unsigned bits) {
  return __uint_as_float((bits >> 9) | 0x3f800000u) - 1.0f;
}

__device__ __forceinline__ float sigm(float x) { return 1.0f / (1.0f + expf(-x)); }

// ----------------------- one-time precompute ---------------------------
__global__ __launch_bounds__(256) void k_fold(
    const float* __restrict__ psi_w, const float* __restrict__ phi_b,
    const float* __restrict__ w_ih0, const float* __restrict__ psi_b,
    const float* __restrict__ b_ih0, const float* __restrict__ b_hh0,
    const float* __restrict__ b_ih1, const float* __restrict__ b_hh1,
    float* __restrict__ vvec, float* __restrict__ bias0,
    float* __restrict__ bias1, float* __restrict__ wohT) {
  int gid = blockIdx.x * 256 + threadIdx.x;
  if (gid < 512) {
    float acc = 0.f;
    for (int j = 0; j < 512; ++j) acc += psi_w[j * 512 + gid] * phi_b[j];
    vvec[gid] = acc;
  } else if (gid < 2560) {
    int j = gid - 512;
    float acc = b_ih0[j] + b_hh0[j];
    const float* wr = w_ih0 + (size_t)j * 576 + 64;
    for (int d = 0; d < 512; ++d) acc += wr[d] * psi_b[d];
    bias0[j] = acc;
  } else if (gid < 4608) {
    int j = gid - 2560;
    bias1[j] = b_ih1[j] + b_hh1[j];
  } else if (gid < 4608 + 131072) {
    int idx = gid - 4608;
    int j = idx >> 6, v = idx & 63;
    wohT[idx] = w_ih0[(size_t)j * 576 + v];
  }
}

// C[m][n] = sum_j A[j][m]*B[j][n]
__global__ __launch_bounds__(256) void k_gemm_tn(
    const float* __restrict__ A, const float* __restrict__ B, float* __restrict__ C,
    int K, int lda, int ldb, int ldc) {
  __shared__ float As[32][33], Bs[32][33];
  int n0 = blockIdx.x * 32, m0 = blockIdx.y * 32;
  int t = threadIdx.x, tx = t & 31, ty = t >> 5;
  float acc[4] = {0.f, 0.f, 0.f, 0.f};
  for (int k0 = 0; k0 < K; k0 += 32) {
    for (int l = t; l < 1024; l += 256) {
      int jj = l >> 5, mm = l & 31;
      As[jj][mm] = A[(size_t)(k0 + jj) * lda + m0 + mm];
      Bs[jj][mm] = B[(size_t)(k0 + jj) * ldb + n0 + mm];
    }
    __syncthreads();
    #pragma unroll 8
    for (int jj = 0; jj < 32; ++jj) {
      float bv = Bs[jj][tx];
      #pragma unroll
      for (int q = 0; q < 4; ++q) acc[q] += As[jj][ty + 8 * q] * bv;
    }
    __syncthreads();
  }
  #pragma unroll
  for (int q = 0; q < 4; ++q) C[(size_t)(m0 + ty + 8 * q) * ldc + n0 + tx] = acc[q];
}

// C[m][n] = sum_k A[m][aoff+k]*B[k][n]
__global__ __launch_bounds__(256) void k_gemm_nn(
    const float* __restrict__ A, const float* __restrict__ B, float* __restrict__ C,
    int K, int lda, int aoff, int ldb, int ldc) {
  __shared__ float As[32][33], Bs[32][33];
  int n0 = blockIdx.x * 32, m0 = blockIdx.y * 32;
  int t = threadIdx.x, tx = t & 31, ty = t >> 5;
  float acc[4] = {0.f, 0.f, 0.f, 0.f};
  for (int k0 = 0; k0 < K; k0 += 32) {
    for (int l = t; l < 1024; l += 256) {
      int r = l >> 5, c = l & 31;
      As[c][r] = A[(size_t)(m0 + r) * lda + aoff + k0 + c];
      Bs[r][c] = B[(size_t)(k0 + r) * ldb + n0 + c];
    }
    __syncthreads();
    #pragma unroll 8
    for (int kk = 0; kk < 32; ++kk) {
      float bv = Bs[kk][tx];
      #pragma unroll
      for (int q = 0; q < 4; ++q) acc[q] += As[kk][ty + 8 * q] * bv;
    }
    __syncthreads();
  }
  #pragma unroll
  for (int q = 0; q < 4; ++q) C[(size_t)(m0 + ty + 8 * q) * ldc + n0 + tx] = acc[q];
}

__global__ __launch_bounds__(128) void k_init(const int* __restrict__ y,
                                              int* __restrict__ z) {
  int t = threadIdx.x;
  if (t < 128) z[t] = y[t * (T_ + 1)];
}

// ----------------------- K_step: b-partitioned fused kernel ------------
// block = one batch b, 512 threads. Phases:
//  1) load s1 column -> LDS
//  2) sqt[d] = vvec[d] + Amat[d,:].s1col   (thread = d, stays in LDS)
//  3) logits partials (8 lanes per vocab) -> ov[64]
//  4) wave0: write out row (step-1), gumbel-argmax + bernoulli -> z[b]
//  5) flash attention over h[b] (online softmax, 16-row chunks) -> ctxT
__global__ __launch_bounds__(512) void k_step(
    const float* __restrict__ h, const float* __restrict__ Amat,
    const float* __restrict__ vvec, const float* __restrict__ outw,
    const float* __restrict__ outb, const int* __restrict__ y,
    const float* __restrict__ s1T, float* __restrict__ ctxT,
    int* __restrict__ z, float* __restrict__ out,
    int step, int do_sample) {
  __shared__ float sl[512];
  __shared__ float sq[512];
  __shared__ float hs[16 * 512];
  __shared__ float es[16];
  __shared__ float ps[16];
  __shared__ float ov[64];
  int b = blockIdx.x, t = threadIdx.x;

  sl[t] = s1T[(size_t)t * 128 + b];
  __syncthreads();

  // sqt (thread = d)
  {
    float a = vvec[t];
    const float* Ar = Amat + (size_t)t * 512;
    #pragma unroll 4
    for (int k = 0; k < 512; k += 4) {
      float4 av = *(const float4*)(Ar + k);
      a += av.x * sl[k] + av.y * sl[k + 1] + av.z * sl[k + 2] + av.w * sl[k + 3];
    }
    sq[t] = a;
  }

  // logits partials: v = t>>3, k-slice = (t&7)*64
  if (do_sample) {
    int v = t >> 3, ks = t & 7;
    const float* wr = outw + (size_t)v * 512 + ks * 64;
    const float* sr = sl + ks * 64;
    float op = 0.f;
    #pragma unroll 4
    for (int k = 0; k < 64; k += 4) {
      float4 wv = *(const float4*)(wr + k);
      op += wv.x * sr[k] + wv.y * sr[k + 1] + wv.z * sr[k + 2] + wv.w * sr[k + 3];
    }
    op += __shfl_xor(op, 1);
    op += __shfl_xor(op, 2);
    op += __shfl_xor(op, 4);
    if (ks == 0) ov[v] = op + outb[v];
  }
  __syncthreads();

  // wave 0: emit logits of step-1, sample z (exact JAX threefry chain)
  if (do_sample && t < 64) {
    float o = ov[t];
    out[((size_t)b * T_ + (step - 1)) * VOC_ + t] = o;
    unsigned ka = 0u, kb2 = (unsigned)(step - 1);
    tf2x32(0u, 42u, ka, kb2);
    unsigned k1a = 0u, k1b = 0u;
    tf2x32(ka, kb2, k1a, k1b);
    unsigned x0 = 0u, x1 = (unsigned)(b * 64 + t);
    tf2x32(k1a, k1b, x0, x1);
    float f = bits_to_unit(x0 ^ x1);
    float u = fmaxf(TF_TINY, f * (1.0f - TF_TINY) + TF_TINY);
    float val = o - logf(-logf(u));
    int idx = t;
    #pragma unroll
    for (int off = 1; off < 64; off <<= 1) {
      float ovv = __shfl_xor(val, off);
      int oi = __shfl_xor(idx, off);
      if (ovv > val || (ovv == val && oi < idx)) { val = ovv; idx = oi; }
    }
    if (t == 0) {
      unsigned k2a = 0u, k2b = 1u;
      tf2x32(ka, kb2, k2a, k2b);
      unsigned y0 = 0u, y1 = (unsigned)b;
      tf2x32(k2a, k2b, y0, y1);
      float ub = bits_to_unit(y0 ^ y1);
      z[b] = (ub < 0.1f) ? idx : y[b * (T_ + 1) + step];
    }
  }

  // flash attention: 32 chunks of 16 rows. lane role: r = t>>5, g = t&31.
  int r = t >> 5, g = t & 31;
  const float* hb = h + (size_t)b * 512 * 512;
  float m = -INFINITY, lsum = 0.f, acc = 0.f;
  for (int r0 = 0; r0 < 512; r0 += 16) {
    __syncthreads();  // protect hs from previous chunk's readers
    const float* hr = hb + (size_t)(r0 + r) * 512 + g * 16;
    float ep = 0.f;
    #pragma unroll
    for (int i = 0; i < 4; ++i) {
      float4 hv = *(const float4*)(hr + i * 4);
      float4 sv = *(const float4*)(sq + g * 16 + i * 4);
      ep += hv.x * sv.x + hv.y * sv.y + hv.z * sv.z + hv.w * sv.w;
      *(float4*)(&hs[r * 512 + g * 16 + i * 4]) = hv;
    }
    ep += __shfl_xor(ep, 1);
    ep += __shfl_xor(ep, 2);
    ep += __shfl_xor(ep, 4);
    ep += __shfl_xor(ep, 8);
    ep += __shfl_xor(ep, 16);
    if (g == 0) es[r] = ep;
    __syncthreads();
    float mc = fmaxf(fmaxf(fmaxf(es[0], es[1]), fmaxf(es[2], es[3])),
                     fmaxf(fmaxf(es[4], es[5]), fmaxf(es[6], es[7])));
    mc = fmaxf(mc, fmaxf(fmaxf(fmaxf(es[8], es[9]), fmaxf(es[10], es[11])),
                         fmaxf(fmaxf(es[12], es[13]), fmaxf(es[14], es[15]))));
    float mn = fmaxf(m, mc);
    if (t < 16) ps[t] = expf(es[t] - mn);
    __syncthreads();
    float sc = expf(m - mn), ls = 0.f, na = acc * sc;
    #pragma unroll
    for (int kk = 0; kk < 16; ++kk) {
      float p = ps[kk];
      ls += p;
      na += p * hs[kk * 512 + t];
    }
    m = mn; lsum = lsum * sc + ls; acc = na;
  }
  ctxT[(size_t)t * 128 + b] = acc / lsum;   // tiny scatter: fine (256 KB tensor)
}

// ----------------------- K_lstm: full-K GEMM + cell epilogue -----------
// grid 256 x 512thr. Block: d-pair. Wave w: dg = w>>2 (d within pair),
// q = w&3 (K-quarter: q<2 -> X0/W0, else X1/W1; kbase=(q&1)*256).
// Thread: lane l -> b-pair (2l, 2l+1); 8 accums = 4 gates x 2 b.
// Waves q!=0 dump partials to LDS; q==0 wave reduces + runs the cell.
__global__ __launch_bounds__(512) void k_lstm(
    const float* __restrict__ X0, const float* __restrict__ W0,
    const float* __restrict__ X1, const float* __restrict__ W1,
    const float* __restrict__ bias, const float* __restrict__ wohT,
    const int* __restrict__ z, float* __restrict__ cT,
    float* __restrict__ sT_out) {
  __shared__ float red[2][3][8][64];   // 12 KB
  int t = threadIdx.x;
  int w = __builtin_amdgcn_readfirstlane(t >> 6);
  int l = t & 63;
  int dg = w >> 2, q = w & 3;
  int d = blockIdx.x * 2 + dg;
  const float* X = (q < 2) ? X0 : X1;
  const float* W = (q < 2) ? W0 : W1;
  int kbase = (q & 1) * 256;
  const float* Wr0 = W + ((size_t)(0 * 512 + d)) * 512 + kbase;
  const float* Wr1 = W + ((size_t)(1 * 512 + d)) * 512 + kbase;
  const float* Wr2 = W + ((size_t)(2 * 512 + d)) * 512 + kbase;
  const float* Wr3 = W + ((size_t)(3 * 512 + d)) * 512 + kbase;
  const float* Xp = X + (size_t)kbase * 128 + l * 2;

  float acc[8] = {0.f, 0.f, 0.f, 0.f, 0.f, 0.f, 0.f, 0.f};
  #pragma unroll 8
  for (int k = 0; k < 256; k += 4) {
    float4 wq0 = *(const float4*)(Wr0 + k);
    float4 wq1 = *(const float4*)(Wr1 + k);
    float4 wq2 = *(const float4*)(Wr2 + k);
    float4 wq3 = *(const float4*)(Wr3 + k);
    const float w0a[4] = {wq0.x, wq0.y, wq0.z, wq0.w};
    const float w1a[4] = {wq1.x, wq1.y, wq1.z, wq1.w};
    const float w2a[4] = {wq2.x, wq2.y, wq2.z, wq2.w};
    const float w3a[4] = {wq3.x, wq3.y, wq3.z, wq3.w};
    #pragma unroll
    for (int kk = 0; kk < 4; ++kk) {
      float2 xv = *(const float2*)(Xp + (size_t)(k + kk) * 128);
      acc[0] = fmaf(xv.x, w0a[kk], acc[0]);
      acc[1] = fmaf(xv.y, w0a[kk], acc[1]);
      acc[2] = fmaf(xv.x, w1a[kk], acc[2]);
      acc[3] = fmaf(xv.y, w1a[kk], acc[3]);
      acc[4] = fmaf(xv.x, w2a[kk], acc[4]);
      acc[5] = fmaf(xv.y, w2a[kk], acc[5]);
      acc[6] = fmaf(xv.x, w3a[kk], acc[6]);
      acc[7] = fmaf(xv.y, w3a[kk], acc[7]);
    }
  }

  if (q != 0) {
    #pragma unroll
    for (int i = 0; i < 8; ++i) red[dg][q - 1][i][l] = acc[i];
  }
  __syncthreads();
  if (q == 0) {
    #pragma unroll
    for (int qq = 0; qq < 3; ++qq)
      #pragma unroll
      for (int i = 0; i < 8; ++i) acc[i] += red[dg][qq][i][l];

    int b0 = l * 2;
    float bi = bias[d], bf = bias[512 + d], bg = bias[1024 + d], bo = bias[1536 + d];
    if (wohT) {
      int za = z[b0], zb = z[b0 + 1];
      acc[0] += wohT[(size_t)d * 64 + za];
      acc[1] += wohT[(size_t)d * 64 + zb];
      acc[2] += wohT[(size_t)(512 + d) * 64 + za];
      acc[3] += wohT[(size_t)(512 + d) * 64 + zb];
      acc[4] += wohT[(size_t)(1024 + d) * 64 + za];
      acc[5] += wohT[(size_t)(1024 + d) * 64 + zb];
      acc[6] += wohT[(size_t)(1536 + d) * 64 + za];
      acc[7] += wohT[(size_t)(1536 + d) * 64 + zb];
    }
    float i0 = sigm(acc[0] + bi), i1 = sigm(acc[1] + bi);
    float f0 = sigm(acc[2] + bf), f1 = sigm(acc[3] + bf);
    float g0 = tanhf(acc[4] + bg), g1 = tanhf(acc[5] + bg);
    float o0 = sigm(acc[6] + bo), o1 = sigm(acc[7] + bo);
    size_t idx = (size_t)d * 128 + b0;
    float2 c = *(float2*)(cT + idx);
    float cn0 = f0 * c.x + i0 * g0;
    float cn1 = f1 * c.y + i1 * g1;
    *(float2*)(cT + idx) = make_float2(cn0, cn1);
    *(float2*)(sT_out + idx) = make_float2(o0 * tanhf(cn0), o1 * tanhf(cn1));
  }
}

// ----------------------- tail: logits of final step --------------------
__global__ __launch_bounds__(64) void k_tail(
    const float* __restrict__ s1T, const float* __restrict__ outw,
    const float* __restrict__ outb, float* __restrict__ out) {
  __shared__ float sl[512];
  int b = blockIdx.x, t = threadIdx.x;
  for (int i = t; i < 512; i += 64) sl[i] = s1T[(size_t)i * 128 + b];
  __syncthreads();
  float o = outb[t];
  const float* wr = outw + (size_t)t * 512;
  #pragma unroll 4
  for (int k = 0; k < 512; k += 4) {
    float4 wv = *(const float4*)(wr + k);
    o += wv.x * sl[k] + wv.y * sl[k + 1] + wv.z * sl[k + 2] + wv.w * sl[k + 3];
  }
  out[((size_t)b * T_ + (T_ - 1)) * VOC_ + t] = o;
}

// =====================================================================
extern "C" void kernel_launch(void* const* d_in, const int* in_sizes, int n_in,
                              void* d_out, int out_size, void* d_ws, size_t ws_size,
                              hipStream_t stream) {
  const float* h     = (const float*)d_in[0];
  const float* phi_w = (const float*)d_in[1];
  const float* phi_b = (const float*)d_in[2];
  const float* psi_w = (const float*)d_in[3];
  const float* psi_b = (const float*)d_in[4];
  const float* w_ih0 = (const float*)d_in[5];
  const float* w_hh0 = (const float*)d_in[6];
  const float* b_ih0 = (const float*)d_in[7];
  const float* b_hh0 = (const float*)d_in[8];
  const float* w_ih1 = (const float*)d_in[9];
  const float* w_hh1 = (const float*)d_in[10];
  const float* b_ih1 = (const float*)d_in[11];
  const float* b_hh1 = (const float*)d_in[12];
  const float* out_w = (const float*)d_in[13];
  const float* out_b = (const float*)d_in[14];
  const int*   y     = (const int*)d_in[15];

  float* out = (float*)d_out;
  float* ws  = (float*)d_ws;

  float* s0buf[2] = {ws + S0A_OFF, ws + S0B_OFF};
  float* cs0   = ws + CS0_OFF;
  float* s1buf[2] = {ws + S1A_OFF, ws + S1B_OFF};
  float* cs1   = ws + CS1_OFF;
  float* ctxT  = ws + CTX_OFF;
  float* Amat  = ws + AMAT_OFF;
  float* W1PSI = ws + W1PSI_OFF;
  float* bias0 = ws + BIAS0_OFF;
  float* bias1 = ws + BIAS1_OFF;
  float* vvec  = ws + VVEC_OFF;
  float* wohT  = ws + WOHT_OFF;
  int*   z     = (int*)(ws + ZB_OFF);

  // zero all recurrent states (s0A,s0B,cs0,s1A,s1B,cs1 contiguous)
  hipMemsetAsync(ws, 0, 6u * 65536u * sizeof(float), stream);

  k_fold<<<531, 256, 0, stream>>>(psi_w, phi_b, w_ih0, psi_b, b_ih0, b_hh0,
                                  b_ih1, b_hh1, vvec, bias0, bias1, wohT);
  k_gemm_tn<<<dim3(16, 16), 256, 0, stream>>>(psi_w, phi_w, Amat, 512, 512, 512, 512);
  k_gemm_nn<<<dim3(16, 64), 256, 0, stream>>>(w_ih0, psi_w, W1PSI, 512, 576, 64, 512, 512);
  k_init<<<1, 128, 0, stream>>>(y, z);

  for (int t = 0; t < T_; ++t) {
    const float* s1in = s1buf[t & 1];
    float* s1out      = s1buf[1 - (t & 1)];
    const float* s0in = s0buf[t & 1];
    float* s0out      = s0buf[1 - (t & 1)];

    k_step<<<128, 512, 0, stream>>>(h, Amat, vvec, out_w, out_b, y,
                                    s1in, ctxT, z, out, t, (t > 0) ? 1 : 0);
    k_lstm<<<256, 512, 0, stream>>>(ctxT, W1PSI, s0in, w_hh0,
                                    bias0, wohT, z, cs0, s0out);
    k_lstm<<<256, 512, 0, stream>>>(s0out, w_ih1, s1in, w_hh1,
                                    bias1, nullptr, nullptr, cs1, s1out);
  }
  // final logits o_127 from s1 after step 127 (lives in buffer 0)
  k_tail<<<128, 64, 0, stream>>>(s1buf[0], out_w, out_b, out);
}